// Round 5
// baseline (133.803 us; speedup 1.0000x reference)
//
#include <hip/hip_runtime.h>

#define S_   96
#define B_   16
#define D_   512
#define HID_ 128
#define M_   (S_ * B_)   // 1536

// Own POD vector types only — no HIP vector classes.
typedef __attribute__((ext_vector_type(4))) float f32x4_t;
typedef __attribute__((ext_vector_type(2))) float f32x2_t;

// Stage 1 (VALU, f32): ws[z][m][h] = sum_d x[m][d] * W1[h][z*512+d]  (+ b1[h] for z=0)
// grid (192, 2), block 256: 8 m-rows/block, each thread: 1 m x 4 h dots over D=512.
__global__ __launch_bounds__(256) void stage1_valu(
    const float* __restrict__ emb,
    const float* __restrict__ embc,
    const float* __restrict__ W1,
    const float* __restrict__ b1,
    float* __restrict__ ws)
{
    const int t  = threadIdx.x;
    const int z  = blockIdx.y;
    const int m  = blockIdx.x * 8 + (t & 7);
    const int h0 = (t >> 3) * 4;

    const float* src = z ? embc : emb;
    const float* xr  = src + m * D_;
    const float* wr  = W1 + h0 * (2 * D_) + z * D_;

    float acc[4] = {0.f, 0.f, 0.f, 0.f};
    for (int d = 0; d < D_; d += 4) {
        f32x4_t x = *(const f32x4_t*)(xr + d);
        #pragma unroll
        for (int hh = 0; hh < 4; ++hh) {
            f32x4_t w = *(const f32x4_t*)(wr + hh * (2 * D_) + d);
            float s = acc[hh];
            s = fmaf(x[0], w[0], s);
            s = fmaf(x[1], w[1], s);
            s = fmaf(x[2], w[2], s);
            s = fmaf(x[3], w[3], s);
            acc[hh] = s;
        }
    }
    float* dst = ws + (size_t)z * (M_ * HID_) + m * HID_;
    #pragma unroll
    for (int hh = 0; hh < 4; ++hh) {
        const float bias = z ? 0.f : b1[h0 + hh];
        dst[h0 + hh] = acc[hh] + bias;
    }
}

// Stage 2: out[i,j,b,c] = relu(ha[i,b,:]+hb[j,b,:]) . W2[c,:] + b2[c]
// grid (6, 6, 16), block 256: one (i,j) pair per thread. f32 in, f32 out.
__global__ __launch_bounds__(256) void stage2(
    const float* __restrict__ ws,
    const float* __restrict__ W2,
    const float* __restrict__ b2,
    float* __restrict__ out)
{
    __shared__ float ha_s[16 * 132];   // stride 132: tj-strided reads only 2-way alias (free)
    __shared__ float hb_s[16 * 132];
    __shared__ float w2_s[2 * HID_];

    const int t  = threadIdx.x;
    const int i0 = blockIdx.x * 16;
    const int j0 = blockIdx.y * 16;
    const int b  = blockIdx.z;

    {
        const int r = t >> 4;
        const int c = (t & 15) * 8;
        const float* pHa = ws + ((i0 + r) * B_ + b) * HID_ + c;
        const float* pHb = ws + (M_ * HID_) + ((j0 + r) * B_ + b) * HID_ + c;
        *(f32x4_t*)&ha_s[r * 132 + c]     = *(const f32x4_t*)pHa;
        *(f32x4_t*)&ha_s[r * 132 + c + 4] = *(const f32x4_t*)(pHa + 4);
        *(f32x4_t*)&hb_s[r * 132 + c]     = *(const f32x4_t*)pHb;
        *(f32x4_t*)&hb_s[r * 132 + c + 4] = *(const f32x4_t*)(pHb + 4);
        w2_s[t] = W2[t];                 // W2 is (2,128) row-major, 256 elems
    }
    __syncthreads();

    const int ti = t >> 4, tj = t & 15;
    const float* pa = &ha_s[ti * 132];
    const float* pb = &hb_s[tj * 132];
    float acc0 = 0.f, acc1 = 0.f;
    #pragma unroll
    for (int h = 0; h < HID_; h += 4) {
        f32x4_t av = *(const f32x4_t*)(pa + h);
        f32x4_t bv = *(const f32x4_t*)(pb + h);
        f32x4_t w0 = *(const f32x4_t*)&w2_s[h];
        f32x4_t w1 = *(const f32x4_t*)&w2_s[HID_ + h];
        #pragma unroll
        for (int q = 0; q < 4; ++q) {
            float v = fmaxf(av[q] + bv[q], 0.f);
            acc0 = fmaf(v, w0[q], acc0);
            acc1 = fmaf(v, w1[q], acc1);
        }
    }

    const int i = i0 + ti, j = j0 + tj;
    const int idx = ((i * S_ + j) * B_ + b) * 2;
    f32x2_t o = { acc0 + b2[0], acc1 + b2[1] };
    *(f32x2_t*)(out + idx) = o;          // idx even -> 8B aligned
}

// Fallback if ws is unusable: recompute ha/hb tiles per block. Correctness-only.
__global__ __launch_bounds__(256) void fused_fallback(
    const float* __restrict__ emb,
    const float* __restrict__ embc,
    const float* __restrict__ W1,
    const float* __restrict__ b1,
    const float* __restrict__ W2,
    const float* __restrict__ b2,
    float* __restrict__ out)
{
    __shared__ float ha_s[16 * 132];
    __shared__ float hb_s[16 * 132];
    __shared__ float w2_s[2 * HID_];

    const int t  = threadIdx.x;
    const int i0 = blockIdx.x * 16;
    const int j0 = blockIdx.y * 16;
    const int b  = blockIdx.z;

    w2_s[t] = W2[t];

    for (int o = t; o < 4096; o += 256) {
        const int side = o >> 11;          // 0: ha, 1: hb
        const int mi   = (o >> 7) & 15;
        const int h    = o & 127;
        const int srow = ((side ? j0 : i0) + mi) * B_ + b;
        const float* x = (side ? embc : emb) + srow * D_;
        const float* w = W1 + h * (2 * D_) + side * D_;
        float s = side ? 0.f : b1[h];
        for (int d = 0; d < D_; d += 4) {
            f32x4_t xv = *(const f32x4_t*)(x + d);
            f32x4_t wv = *(const f32x4_t*)(w + d);
            s = fmaf(xv[0], wv[0], s);
            s = fmaf(xv[1], wv[1], s);
            s = fmaf(xv[2], wv[2], s);
            s = fmaf(xv[3], wv[3], s);
        }
        (side ? hb_s : ha_s)[mi * 132 + h] = s;
    }
    __syncthreads();

    const int ti = t >> 4, tj = t & 15;
    const float* pa = &ha_s[ti * 132];
    const float* pb = &hb_s[tj * 132];
    float acc0 = 0.f, acc1 = 0.f;
    #pragma unroll
    for (int h = 0; h < HID_; h += 4) {
        f32x4_t av = *(const f32x4_t*)(pa + h);
        f32x4_t bv = *(const f32x4_t*)(pb + h);
        f32x4_t w0 = *(const f32x4_t*)&w2_s[h];
        f32x4_t w1 = *(const f32x4_t*)&w2_s[HID_ + h];
        #pragma unroll
        for (int q = 0; q < 4; ++q) {
            float v = fmaxf(av[q] + bv[q], 0.f);
            acc0 = fmaf(v, w0[q], acc0);
            acc1 = fmaf(v, w1[q], acc1);
        }
    }
    const int i = i0 + ti, j = j0 + tj;
    const int idx = ((i * S_ + j) * B_ + b) * 2;
    f32x2_t ov = { acc0 + b2[0], acc1 + b2[1] };
    *(f32x2_t*)(out + idx) = ov;
}

extern "C" void kernel_launch(void* const* d_in, const int* in_sizes, int n_in,
                              void* d_out, int out_size, void* d_ws, size_t ws_size,
                              hipStream_t stream) {
    const float* emb  = (const float*)d_in[0];
    // d_in[1] = umask (unused), d_in[2] = qmask (unused)
    const float* embc = (const float*)d_in[3];
    const float* W1   = (const float*)d_in[4];
    const float* b1   = (const float*)d_in[5];
    const float* W2   = (const float*)d_in[6];
    const float* b2   = (const float*)d_in[7];
    float* out = (float*)d_out;

    const size_t need = (size_t)2 * M_ * HID_ * sizeof(float);  // 1.57 MB
    if (d_ws != nullptr && ws_size >= need) {
        float* ws = (float*)d_ws;   // ha: [0, 196608) f32, hb: [196608, 393216)
        stage1_valu<<<dim3(192, 2), 256, 0, stream>>>(emb, embc, W1, b1, ws);
        stage2<<<dim3(6, 6, 16), 256, 0, stream>>>(ws, W2, b2, out);
    } else {
        fused_fallback<<<dim3(6, 6, 16), 256, 0, stream>>>(emb, embc, W1, b1, W2, b2, out);
    }
}

// Round 6
// 91.193 us; speedup vs baseline: 1.4673x; 1.4673x over previous
//
#include <hip/hip_runtime.h>

#define S_   96
#define B_   16
#define D_   512
#define HID_ 128
#define M_   (S_ * B_)   // 1536

// Own POD vector types only — no HIP vector classes (uint4 etc. are non-POD
// classes in HIP and poison unions / reinterprets).
typedef __attribute__((ext_vector_type(4))) float        f32x4_t;
typedef __attribute__((ext_vector_type(2))) float        f32x2_t;
typedef __attribute__((ext_vector_type(4))) unsigned int u32x4_t;
typedef __attribute__((ext_vector_type(8))) short        short8;   // bf16x8 MFMA frag (guide-verified type)

// Split 8 f32 into hi/lo truncated-bf16 fragments. hi = trunc16(x) (exact field
// chop); r = x - hi is exactly representable; lo = trunc16(r). Dropped terms
// (lo*lo, trunc of r) are ~2^-16 relative -> f32-grade GEMM via 3 bf16 MFMAs.
static __device__ __forceinline__ void split8(f32x4_t a, f32x4_t b,
                                              short8& hi, short8& lo) {
    float f[8];
    #pragma unroll
    for (int j = 0; j < 4; ++j) { f[j] = a[j]; f[4 + j] = b[j]; }
    unsigned int hb[8], lb[8];
    #pragma unroll
    for (int j = 0; j < 8; ++j) {
        unsigned int u = __float_as_uint(f[j]);
        float hf = __uint_as_float(u & 0xffff0000u);
        hb[j] = u >> 16;
        lb[j] = __float_as_uint(f[j] - hf) >> 16;
    }
    union { u32x4_t u; short8 s; } H, L;
    #pragma unroll
    for (int j = 0; j < 4; ++j) {
        H.u[j] = hb[2 * j] | (hb[2 * j + 1] << 16);
        L.u[j] = lb[2 * j] | (lb[2 * j + 1] << 16);
    }
    hi = H.s; lo = L.s;
}

// Stage 1 (MFMA, split-bf16): ws[z][m][h] = sum_d x[m][d]*W1[h][z*512+d] (+b1 for z=0)
// grid (48, 8), block 256 = 4 waves; wave handles one 16(m)x16(h) tile, K=512.
// 1536 waves total = 6 waves/CU.
__global__ __launch_bounds__(256) void stage1_mfma(
    const float* __restrict__ emb,
    const float* __restrict__ embc,
    const float* __restrict__ W1,
    const float* __restrict__ b1,
    float* __restrict__ ws)
{
    const int wave = threadIdx.x >> 6;
    const int lane = threadIdx.x & 63;
    const int gm = blockIdx.x * 64 + wave * 16;   // combined row in [0,3072); 1536 boundary is block-aligned
    const int z  = (gm >= M_) ? 1 : 0;
    const int m0 = gm - z * M_;
    const int n0 = blockIdx.y * 16;

    const int rsel = lane & 15;
    const int kq   = (lane >> 4) * 8;
    const float* xr = (z ? embc : emb) + (m0 + rsel) * D_ + kq;
    const float* wr = W1 + (n0 + rsel) * (2 * D_) + z * D_ + kq;

    f32x4_t acc = {0.f, 0.f, 0.f, 0.f};
    #pragma unroll
    for (int k = 0; k < D_; k += 32) {
        f32x4_t xa = *(const f32x4_t*)(xr + k);
        f32x4_t xb = *(const f32x4_t*)(xr + k + 4);
        f32x4_t wa = *(const f32x4_t*)(wr + k);
        f32x4_t wb = *(const f32x4_t*)(wr + k + 4);
        short8 xhi, xlo, whi, wlo;
        split8(xa, xb, xhi, xlo);
        split8(wa, wb, whi, wlo);
        acc = __builtin_amdgcn_mfma_f32_16x16x32_bf16(xhi, whi, acc, 0, 0, 0);
        acc = __builtin_amdgcn_mfma_f32_16x16x32_bf16(xhi, wlo, acc, 0, 0, 0);
        acc = __builtin_amdgcn_mfma_f32_16x16x32_bf16(xlo, whi, acc, 0, 0, 0);
    }

    // C/D layout: col(h)=lane&15, row(m)=(lane>>4)*4+reg  [m89/m91 HW-verified]
    const int h = n0 + rsel;
    const float bias = z ? 0.f : b1[h];
    const int mrow = m0 + (lane >> 4) * 4;
    float* dst = ws + (size_t)z * (M_ * HID_);
    #pragma unroll
    for (int r = 0; r < 4; ++r) {
        dst[(mrow + r) * HID_ + h] = acc[r] + bias;
    }
}

// Stage 2 (unchanged from passing round): out[i,j,b,c] = relu(ha+hb).W2[c,:]+b2[c]
// grid (6, 6, 16), block 256: one (i,j) pair per thread. f32 in, f32 out.
__global__ __launch_bounds__(256) void stage2(
    const float* __restrict__ ws,
    const float* __restrict__ W2,
    const float* __restrict__ b2,
    float* __restrict__ out)
{
    __shared__ float ha_s[16 * 132];
    __shared__ float hb_s[16 * 132];
    __shared__ float w2_s[2 * HID_];

    const int t  = threadIdx.x;
    const int i0 = blockIdx.x * 16;
    const int j0 = blockIdx.y * 16;
    const int b  = blockIdx.z;

    {
        const int r = t >> 4;
        const int c = (t & 15) * 8;
        const float* pHa = ws + ((i0 + r) * B_ + b) * HID_ + c;
        const float* pHb = ws + (M_ * HID_) + ((j0 + r) * B_ + b) * HID_ + c;
        *(f32x4_t*)&ha_s[r * 132 + c]     = *(const f32x4_t*)pHa;
        *(f32x4_t*)&ha_s[r * 132 + c + 4] = *(const f32x4_t*)(pHa + 4);
        *(f32x4_t*)&hb_s[r * 132 + c]     = *(const f32x4_t*)pHb;
        *(f32x4_t*)&hb_s[r * 132 + c + 4] = *(const f32x4_t*)(pHb + 4);
        w2_s[t] = W2[t];
    }
    __syncthreads();

    const int ti = t >> 4, tj = t & 15;
    const float* pa = &ha_s[ti * 132];
    const float* pb = &hb_s[tj * 132];
    float acc0 = 0.f, acc1 = 0.f;
    #pragma unroll
    for (int h = 0; h < HID_; h += 4) {
        f32x4_t av = *(const f32x4_t*)(pa + h);
        f32x4_t bv = *(const f32x4_t*)(pb + h);
        f32x4_t w0 = *(const f32x4_t*)&w2_s[h];
        f32x4_t w1 = *(const f32x4_t*)&w2_s[HID_ + h];
        #pragma unroll
        for (int q = 0; q < 4; ++q) {
            float v = fmaxf(av[q] + bv[q], 0.f);
            acc0 = fmaf(v, w0[q], acc0);
            acc1 = fmaf(v, w1[q], acc1);
        }
    }

    const int i = i0 + ti, j = j0 + tj;
    const int idx = ((i * S_ + j) * B_ + b) * 2;
    f32x2_t o = { acc0 + b2[0], acc1 + b2[1] };
    *(f32x2_t*)(out + idx) = o;
}

// Fallback if ws is unusable: recompute ha/hb tiles per block. Correctness-only.
__global__ __launch_bounds__(256) void fused_fallback(
    const float* __restrict__ emb,
    const float* __restrict__ embc,
    const float* __restrict__ W1,
    const float* __restrict__ b1,
    const float* __restrict__ W2,
    const float* __restrict__ b2,
    float* __restrict__ out)
{
    __shared__ float ha_s[16 * 132];
    __shared__ float hb_s[16 * 132];
    __shared__ float w2_s[2 * HID_];

    const int t  = threadIdx.x;
    const int i0 = blockIdx.x * 16;
    const int j0 = blockIdx.y * 16;
    const int b  = blockIdx.z;

    w2_s[t] = W2[t];

    for (int o = t; o < 4096; o += 256) {
        const int side = o >> 11;
        const int mi   = (o >> 7) & 15;
        const int h    = o & 127;
        const int srow = ((side ? j0 : i0) + mi) * B_ + b;
        const float* x = (side ? embc : emb) + srow * D_;
        const float* w = W1 + h * (2 * D_) + side * D_;
        float s = side ? 0.f : b1[h];
        for (int d = 0; d < D_; d += 4) {
            f32x4_t xv = *(const f32x4_t*)(x + d);
            f32x4_t wv = *(const f32x4_t*)(w + d);
            s = fmaf(xv[0], wv[0], s);
            s = fmaf(xv[1], wv[1], s);
            s = fmaf(xv[2], wv[2], s);
            s = fmaf(xv[3], wv[3], s);
        }
        (side ? hb_s : ha_s)[mi * 132 + h] = s;
    }
    __syncthreads();

    const int ti = t >> 4, tj = t & 15;
    const float* pa = &ha_s[ti * 132];
    const float* pb = &hb_s[tj * 132];
    float acc0 = 0.f, acc1 = 0.f;
    #pragma unroll
    for (int h = 0; h < HID_; h += 4) {
        f32x4_t av = *(const f32x4_t*)(pa + h);
        f32x4_t bv = *(const f32x4_t*)(pb + h);
        f32x4_t w0 = *(const f32x4_t*)&w2_s[h];
        f32x4_t w1 = *(const f32x4_t*)&w2_s[HID_ + h];
        #pragma unroll
        for (int q = 0; q < 4; ++q) {
            float v = fmaxf(av[q] + bv[q], 0.f);
            acc0 = fmaf(v, w0[q], acc0);
            acc1 = fmaf(v, w1[q], acc1);
        }
    }
    const int i = i0 + ti, j = j0 + tj;
    const int idx = ((i * S_ + j) * B_ + b) * 2;
    f32x2_t ov = { acc0 + b2[0], acc1 + b2[1] };
    *(f32x2_t*)(out + idx) = ov;
}

extern "C" void kernel_launch(void* const* d_in, const int* in_sizes, int n_in,
                              void* d_out, int out_size, void* d_ws, size_t ws_size,
                              hipStream_t stream) {
    const float* emb  = (const float*)d_in[0];
    // d_in[1] = umask (unused), d_in[2] = qmask (unused)
    const float* embc = (const float*)d_in[3];
    const float* W1   = (const float*)d_in[4];
    const float* b1   = (const float*)d_in[5];
    const float* W2   = (const float*)d_in[6];
    const float* b2   = (const float*)d_in[7];
    float* out = (float*)d_out;

    const size_t need = (size_t)2 * M_ * HID_ * sizeof(float);  // 1.57 MB
    if (d_ws != nullptr && ws_size >= need) {
        float* ws = (float*)d_ws;   // ha: [0, 196608) f32, hb: [196608, 393216)
        stage1_mfma<<<dim3(48, 8), 256, 0, stream>>>(emb, embc, W1, b1, ws);
        stage2<<<dim3(6, 6, 16), 256, 0, stream>>>(ws, W2, b2, out);
    } else {
        fused_fallback<<<dim3(6, 6, 16), 256, 0, stream>>>(emb, embc, W1, b1, W2, b2, out);
    }
}